// Round 8
// baseline (196.079 us; speedup 1.0000x reference)
//
#include <hip/hip_runtime.h>
#include <hip/hip_bf16.h>

// Problem constants (B=8, C=512, N=4096, heads=8, splits=4)
#define BATCH 8
#define CIN   512
#define NTOK  4096
#define CH    256      // C2 = C/2
#define J3    768      // 3*C2
#define NH    8        // heads
#define DH    32       // head dim
#define NCH   1024     // tokens per chunk (N / SPLITS)

typedef _Float16 F16;
typedef _Float16 f16x8 __attribute__((ext_vector_type(8)));
typedef _Float16 f16x4 __attribute__((ext_vector_type(4)));
typedef _Float16 f16x2 __attribute__((ext_vector_type(2)));
typedef float    f32x4  __attribute__((ext_vector_type(4)));
typedef float    f32x16 __attribute__((ext_vector_type(16)));

// scale * log2(e) = (1/sqrt(32)) * 1.4426950408889634
#define QSCALE 0.25503483f

// ---------------------------------------------------------------------------
// Kernel 0: fuse reduction (Wr,br) with toQKV (Wqkv) -> fp16 combined weight.
// Q-rows (j<256) pre-scaled by QSCALE so attention can use exp2 directly.
// ---------------------------------------------------------------------------
__global__ __launch_bounds__(256) void fuse_weights_kernel(
    const float* __restrict__ Wr, const float* __restrict__ br,
    const float* __restrict__ Wqkv,
    F16* __restrict__ Wcomb, float* __restrict__ bcomb)
{
    const int j = blockIdx.x;
    const int tid = threadIdx.x;
    const float qs = (j < 256) ? QSCALE : 1.0f;
    float acc0 = 0.f, acc1 = 0.f;
    for (int c2 = 0; c2 < CH; ++c2) {
        const float w = Wqkv[c2 * J3 + j];
        acc0 = fmaf(w, Wr[c2 * CIN + tid], acc0);
        acc1 = fmaf(w, Wr[c2 * CIN + tid + 256], acc1);
    }
    Wcomb[j * CIN + tid] = (F16)(acc0 * qs);
    Wcomb[j * CIN + tid + 256] = (F16)(acc1 * qs);
    if (tid == 0) {
        float s = 0.f;
        for (int c2 = 0; c2 < CH; ++c2) s = fmaf(Wqkv[c2 * J3 + j], br[c2], s);
        bcomb[j] = s * qs;
    }
}

__global__ __launch_bounds__(256) void convert_we_kernel(
    const float* __restrict__ We, F16* __restrict__ We16)
{
    const int i = blockIdx.x * 256 + threadIdx.x;
    We16[i] = (F16)We[i];
}

// ---------------------------------------------------------------------------
// transpose-convert x [B][512][4096] f32 -> xt [B][4096][512] f16
// ---------------------------------------------------------------------------
__global__ __launch_bounds__(256) void transpose_convert_kernel(
    const float* __restrict__ x, F16* __restrict__ xt)
{
    const int b = blockIdx.z;
    const int c0 = blockIdx.y * 64;
    const int n0 = blockIdx.x * 64;
    const int t = threadIdx.x;

    __shared__ F16 T[64][66];

    const float* xb = x + ((size_t)b * CIN + c0) * NTOK + n0;
#pragma unroll
    for (int r = 0; r < 16; ++r) {
        const int c = r * 4 + (t >> 6), n = t & 63;
        T[c][n] = (F16)xb[(size_t)c * NTOK + n];
    }
    __syncthreads();
    F16* xtb = xt + ((size_t)b * NTOK + n0) * CIN + c0;
#pragma unroll
    for (int r = 0; r < 16; ++r) {
        const int n = r * 4 + (t >> 6), c = t & 63;
        xtb[(size_t)n * CIN + c] = T[c][n];
    }
}

// ---------------------------------------------------------------------------
// GEMM1: Y = Wcomb * xt^T.  2-phase double-buffered staging (T3-lite):
// stage K-step t+1 BEFORE computing step t; one __syncthreads per iter.
//   j <  512 (q,k): token-major QKb[b][n][512] via LDS retile (coalesced)
//   j >= 512 (v):   d-major    Vd[b][j-512][n] via transposed LDS retile
// ---------------------------------------------------------------------------
__global__ __launch_bounds__(256) void gemm1_kernel(
    const F16* __restrict__ A,      // Wcomb [768][512]
    const F16* __restrict__ B,      // xt [B][4096][512]
    const float* __restrict__ bias, // bcomb [768]
    F16* __restrict__ QKb,          // [B][4096][512]
    F16* __restrict__ Vd)           // [B][256][4096]
{
    const int b  = blockIdx.z;
    const int j0 = blockIdx.y * 128;
    const int n0 = blockIdx.x * 128;
    const int tid = threadIdx.x;
    const int w = tid >> 6, l = tid & 63;
    const int wr = w >> 1, wc = w & 1;
    const int cl = l & 15, rg = l >> 4;

    __shared__ __align__(16) F16 Ash[2][4096];    // 16 KB
    __shared__ __align__(16) F16 Bsh[2][4096];    // 16 KB
    __shared__ __align__(16) F16 Esh[32 * 136];   // epilogue retile (8.7 KB)

    f32x4 acc[4][4];
#pragma unroll
    for (int i = 0; i < 4; ++i)
#pragma unroll
        for (int j = 0; j < 4; ++j) acc[i][j] = (f32x4){0.f, 0.f, 0.f, 0.f};

    const F16* Bb = B + (size_t)b * NTOK * CIN;
    const int frag_off = rg * 1024 + cl * 8;

    const F16* gA0 = A  + (size_t)(j0 + l) * CIN      + w * 8;
    const F16* gA1 = A  + (size_t)(j0 + 64 + l) * CIN + w * 8;
    const F16* gB0 = Bb + (size_t)(n0 + l) * CIN      + w * 8;
    const F16* gB1 = Bb + (size_t)(n0 + 64 + l) * CIN + w * 8;

#define G1_STAGE(bu, ck)                                                       \
    do {                                                                       \
        __builtin_amdgcn_global_load_lds(                                      \
            (const __attribute__((address_space(1))) void*)(gA0 + (ck)),       \
            (__attribute__((address_space(3))) void*)&Ash[bu][w * 1024],       \
            16, 0, 0);                                                         \
        __builtin_amdgcn_global_load_lds(                                      \
            (const __attribute__((address_space(1))) void*)(gA1 + (ck)),       \
            (__attribute__((address_space(3))) void*)&Ash[bu][w * 1024 + 512], \
            16, 0, 0);                                                         \
        __builtin_amdgcn_global_load_lds(                                      \
            (const __attribute__((address_space(1))) void*)(gB0 + (ck)),       \
            (__attribute__((address_space(3))) void*)&Bsh[bu][w * 1024],       \
            16, 0, 0);                                                         \
        __builtin_amdgcn_global_load_lds(                                      \
            (const __attribute__((address_space(1))) void*)(gB1 + (ck)),       \
            (__attribute__((address_space(3))) void*)&Bsh[bu][w * 1024 + 512], \
            16, 0, 0);                                                         \
    } while (0)

    G1_STAGE(0, 0);
    __syncthreads();

    for (int t = 0; t < 16; ++t) {
        const int cur = t & 1;
        if (t < 15) G1_STAGE(cur ^ 1, (t + 1) * 32);

        f16x8 af[4], bfr[4];
#pragma unroll
        for (int f = 0; f < 4; ++f) {
            af[f]  = *(const f16x8*)&Ash[cur][frag_off + (wr * 64 + f * 16) * 8];
            bfr[f] = *(const f16x8*)&Bsh[cur][frag_off + (wc * 64 + f * 16) * 8];
        }
#pragma unroll
        for (int i = 0; i < 4; ++i)
#pragma unroll
            for (int j = 0; j < 4; ++j)
                acc[i][j] = __builtin_amdgcn_mfma_f32_16x16x32_f16(
                    af[i], bfr[j], acc[i][j], 0, 0, 0);
        __syncthreads();   // drains prefetch vmcnt + guards buffer reuse
    }
#undef G1_STAGE

    if (j0 < 512) {
        // ---- retile epilogue: acc -> LDS [n-local 32][j-local 128+8] -> QKb
        // chunk c covers n-local [c*32, c*32+32), written by waves wc==c>>1,
        // then ALL 256 threads read 32B each (4096 F16 = full chunk).
        const size_t bN = (size_t)b * NTOK;
#pragma unroll
        for (int c = 0; c < 4; ++c) {
            __syncthreads();
            if (wc == (c >> 1)) {
                const int jnb = (c & 1) * 2;
#pragma unroll
                for (int i = 0; i < 4; ++i) {
#pragma unroll
                    for (int jj = 0; jj < 2; ++jj) {
                        const int jn = jnb + jj;
                        const int nl = jj * 16 + cl;               // 0..31
                        const int jl = wr * 64 + i * 16 + rg * 4;  // 0..124
                        const int jg = j0 + jl;
                        f16x4 v;
#pragma unroll
                        for (int r = 0; r < 4; ++r)
                            v[r] = (F16)(acc[i][jn][r] + bias[jg + r]);
                        *(f16x4*)&Esh[nl * 136 + jl] = v;
                    }
                }
            }
            __syncthreads();
            const int rr = tid >> 3, ss = tid & 7;   // row, 32B-slot
            const f16x8 ov0 = *(const f16x8*)&Esh[rr * 136 + ss * 16];
            const f16x8 ov1 = *(const f16x8*)&Esh[rr * 136 + ss * 16 + 8];
            F16* dst = &QKb[(bN + n0 + c * 32 + rr) * 512 + j0 + ss * 16];
            *(f16x8*)dst = ov0;
            *(f16x8*)(dst + 8) = ov1;
        }
    } else {
        // ---- V retile (transposed): chunk c covers j-local 32 rows
        // [ (c>>1)*64 + (c&1)*32 .. +32 ), written by waves wr==c>>1.
        // Esh as [j-row 32][n 128] pitch 136; readback 2x f16x8 per thread,
        // stores 16B-coalesced to d-major Vd.
        const size_t bD = (size_t)b * CH;
#pragma unroll
        for (int c = 0; c < 4; ++c) {
            __syncthreads();
            if (wr == (c >> 1)) {
                const int ib = (c & 1) * 2;
#pragma unroll
                for (int ii = 0; ii < 2; ++ii) {
                    const int i = ib + ii;
                    const int jg = j0 + (c >> 1) * 64 + i * 16 + rg * 4;
#pragma unroll
                    for (int jn = 0; jn < 4; ++jn) {
                        const int nl = wc * 64 + jn * 16 + cl;     // 0..127
#pragma unroll
                        for (int r = 0; r < 4; ++r)
                            Esh[(ii * 16 + rg * 4 + r) * 136 + nl] =
                                (F16)(acc[i][jn][r] + bias[jg + r]);
                    }
                }
            }
            __syncthreads();
            const int rr = tid >> 3, ss = tid & 7;   // row (j), 32B-slot (n)
            const f16x8 ov0 = *(const f16x8*)&Esh[rr * 136 + ss * 16];
            const f16x8 ov1 = *(const f16x8*)&Esh[rr * 136 + ss * 16 + 8];
            const int dg = (j0 - 512) + (c >> 1) * 64 + (c & 1) * 32 + rr;
            F16* dst = &Vd[(bD + dg) * NTOK + n0 + ss * 16];
            *(f16x8*)dst = ov0;
            *(f16x8*)(dst + 8) = ov1;
        }
    }
}

// ---------------------------------------------------------------------------
// MFMA attention, 32x32x16, lane-local softmax. (unchanged from R7)
// Swapped QK^T: sacc = mfma(K,Q) -> S^T, lane = one q-column, 16 nk values.
// PV uses sigma-permuted contraction order so the A-fragment IS the lane's
// own 16 exp2 values; V B-frags absorb sigma via b64 reads.
// ---------------------------------------------------------------------------
__global__ __launch_bounds__(256) void attn_mfma_kernel(
    const F16* __restrict__ QK,   // [B][4096][512]: q cols 0-255 (prescaled), k 256-511
    const F16* __restrict__ Vd,   // [B][256][4096]
    F16* __restrict__ O)          // [B][4096][256]
{
    // XCD-chunked swizzle: the 8 q-blocks sharing one (b,h,s) K/V -> one XCD
    const int bid = blockIdx.x;
    const int xcd = bid & 7, tt = bid >> 3;
    const int qb = tt & 7;
    const int pr = xcd * 32 + (tt >> 3);
    const int s = pr & 3, bh = pr >> 2;
    const int b = bh >> 3, h = bh & 7;
    const int tid = threadIdx.x;
    const int w = tid >> 6, l = tid & 63;
    const int ln = l & 31;          // q-col (QK) / d-col (PV)
    const int hi = l >> 5;

    __shared__ __align__(16) F16 Klds[2][64 * 40];   // [nk][d], 80B rows
    __shared__ __align__(16) F16 Vlds[2][32 * 68];   // [d][nk], 136B rows

    const size_t bN = (size_t)b * NTOK + (size_t)s * NCH;
    const int q0 = qb * 128 + w * 32;

    // Q B-frags (d 0-15 / 16-31), prescaled by QSCALE*log2e in GEMM1
    const F16* Qp = QK + (bN + q0 + ln) * 512 + h * DH + hi * 8;
    const f16x8 qf0 = *(const f16x8*)Qp;
    const f16x8 qf1 = *(const f16x8*)(Qp + 16);

    // staging sources (one 16B piece per thread per tile)
    const F16* Kg = QK + (bN + (tid & 63)) * 512 + 256 + h * DH + (tid >> 6) * 8;
    const F16* Vg = Vd + ((size_t)b * CH + h * DH + (tid & 31)) * NTOK
                       + (size_t)s * NCH + (tid >> 5) * 8;
    const int kw = (tid & 63) * 40 + (tid >> 6) * 8;
    const int vw = (tid & 31) * 68 + (tid >> 5) * 8;

    f16x8 kreg = *(const f16x8*)Kg;
    f16x8 vreg = *(const f16x8*)Vg;

    const f16x8 ones = {(F16)1.f, (F16)1.f, (F16)1.f, (F16)1.f,
                        (F16)1.f, (F16)1.f, (F16)1.f, (F16)1.f};

    f32x16 oacc = (f32x16)(0.0f);
    f32x16 lacc = (f32x16)(0.0f);

    // prologue: fill buffer 0
    *(f16x8*)&Klds[0][kw] = kreg;
    *(f16x4*)&Vlds[0][vw] = __builtin_shufflevector(vreg, vreg, 0, 1, 2, 3);
    *(f16x4*)&Vlds[0][vw + 4] = __builtin_shufflevector(vreg, vreg, 4, 5, 6, 7);

    for (int t = 0; t < 16; ++t) {
        const int cur = t & 1, nxt = cur ^ 1;
        __syncthreads();
        if (t < 15) {
            kreg = *(const f16x8*)(Kg + (size_t)(t + 1) * 64 * 512);
            vreg = *(const f16x8*)(Vg + (t + 1) * 64);
        }
        const F16* Kb = &Klds[cur][0];
        const F16* Vb = &Vlds[cur][0];
#pragma unroll
        for (int u = 0; u < 2; ++u) {
            const int nkb = u * 32;
            // K A-frags: row nk = ln, k = d = hi*8+e (two d-halves)
            const f16x8 kf0 = *(const f16x8*)&Kb[(nkb + ln) * 40 + hi * 8];
            const f16x8 kf1 = *(const f16x8*)&Kb[(nkb + ln) * 40 + 16 + hi * 8];
            f32x16 sacc = (f32x16)(0.0f);
            __builtin_amdgcn_s_setprio(1);
            sacc = __builtin_amdgcn_mfma_f32_32x32x16_f16(kf0, qf0, sacc, 0, 0, 0);
            sacc = __builtin_amdgcn_mfma_f32_32x32x16_f16(kf1, qf1, sacc, 0, 0, 0);
            __builtin_amdgcn_s_setprio(0);

            // softmax numerator: exp2 -> pkrtz-packed f16; registers are
            // already in sigma-order for the PV A-fragments.
            union { f16x8 v; f16x2 h[4]; } pu0, pu1;
#pragma unroll
            for (int e = 0; e < 4; ++e) {
                pu0.h[e] = __builtin_bit_cast(f16x2, __builtin_amdgcn_cvt_pkrtz(
                    __builtin_amdgcn_exp2f(sacc[2 * e]),
                    __builtin_amdgcn_exp2f(sacc[2 * e + 1])));
                pu1.h[e] = __builtin_bit_cast(f16x2, __builtin_amdgcn_cvt_pkrtz(
                    __builtin_amdgcn_exp2f(sacc[8 + 2 * e]),
                    __builtin_amdgcn_exp2f(sacc[8 + 2 * e + 1])));
            }

            // V B-frags in sigma order: nk = (e&3) + 8*((e>>2)&1) + 4*hi (+16)
            const int vbase = ln * 68 + nkb + 4 * hi;
            const f16x4 v00 = *(const f16x4*)&Vb[vbase];
            const f16x4 v01 = *(const f16x4*)&Vb[vbase + 8];
            const f16x4 v10 = *(const f16x4*)&Vb[vbase + 16];
            const f16x4 v11 = *(const f16x4*)&Vb[vbase + 24];
            const f16x8 vf0 = __builtin_shufflevector(v00, v01, 0, 1, 2, 3, 4, 5, 6, 7);
            const f16x8 vf1 = __builtin_shufflevector(v10, v11, 0, 1, 2, 3, 4, 5, 6, 7);

            __builtin_amdgcn_s_setprio(1);
            oacc = __builtin_amdgcn_mfma_f32_32x32x16_f16(pu0.v, vf0, oacc, 0, 0, 0);
            oacc = __builtin_amdgcn_mfma_f32_32x32x16_f16(pu1.v, vf1, oacc, 0, 0, 0);
            lacc = __builtin_amdgcn_mfma_f32_32x32x16_f16(pu0.v, ones, lacc, 0, 0, 0);
            lacc = __builtin_amdgcn_mfma_f32_32x32x16_f16(pu1.v, ones, lacc, 0, 0, 0);
            __builtin_amdgcn_s_setprio(0);
        }
        if (t < 15) {
            *(f16x8*)&Klds[nxt][kw] = kreg;
            *(f16x4*)&Vlds[nxt][vw] =
                __builtin_shufflevector(vreg, vreg, 0, 1, 2, 3);
            *(f16x4*)&Vlds[nxt][vw + 4] =
                __builtin_shufflevector(vreg, vreg, 4, 5, 6, 7);
        }
    }

    // lacc[r] = lsum for q-row (r&3)+8*(r>>2)+4*hi -- same map as oacc.
    F16* Op = O + (bN + q0) * CH + h * DH + ln;
#pragma unroll
    for (int r = 0; r < 16; ++r) {
        const int qr = (r & 3) + 8 * (r >> 2) + 4 * hi;
        const float invr = __builtin_amdgcn_rcpf(lacc[r]);
        Op[(size_t)qr * CH] = (F16)(oacc[r] * invr);
    }
}

// ---------------------------------------------------------------------------
// GEMM2: out[b][co][n] = sum_c2 We[co][c2] * O[b][n][c2] + be[co]   (f32 out)
// 2-phase double-buffered staging, same as GEMM1.
// ---------------------------------------------------------------------------
__global__ __launch_bounds__(256) void gemm2_kernel(
    const F16* __restrict__ A,      // We16 [512][256]
    const F16* __restrict__ B,      // Obuf [B][4096][256]
    const float* __restrict__ bias, // be [512]
    float* __restrict__ Y)          // [B][512][4096]
{
    const int b  = blockIdx.z;
    const int j0 = blockIdx.y * 128;
    const int n0 = blockIdx.x * 128;
    const int tid = threadIdx.x;
    const int w = tid >> 6, l = tid & 63;
    const int wr = w >> 1, wc = w & 1;
    const int cl = l & 15, rg = l >> 4;

    __shared__ __align__(16) F16 Ash[2][4096];
    __shared__ __align__(16) F16 Bsh[2][4096];

    f32x4 acc[4][4];
#pragma unroll
    for (int i = 0; i < 4; ++i)
#pragma unroll
        for (int j = 0; j < 4; ++j) acc[i][j] = (f32x4){0.f, 0.f, 0.f, 0.f};

    const F16* Bb = B + (size_t)b * NTOK * CH;
    const int frag_off = rg * 1024 + cl * 8;

    const F16* gA0 = A  + (size_t)(j0 + l) * CH      + w * 8;
    const F16* gA1 = A  + (size_t)(j0 + 64 + l) * CH + w * 8;
    const F16* gB0 = Bb + (size_t)(n0 + l) * CH      + w * 8;
    const F16* gB1 = Bb + (size_t)(n0 + 64 + l) * CH + w * 8;

#define G2_STAGE(bu, ck)                                                       \
    do {                                                                       \
        __builtin_amdgcn_global_load_lds(                                      \
            (const __attribute__((address_space(1))) void*)(gA0 + (ck)),       \
            (__attribute__((address_space(3))) void*)&Ash[bu][w * 1024],       \
            16, 0, 0);                                                         \
        __builtin_amdgcn_global_load_lds(                                      \
            (const __attribute__((address_space(1))) void*)(gA1 + (ck)),       \
            (__attribute__((address_space(3))) void*)&Ash[bu][w * 1024 + 512], \
            16, 0, 0);                                                         \
        __builtin_amdgcn_global_load_lds(                                      \
            (const __attribute__((address_space(1))) void*)(gB0 + (ck)),       \
            (__attribute__((address_space(3))) void*)&Bsh[bu][w * 1024],       \
            16, 0, 0);                                                         \
        __builtin_amdgcn_global_load_lds(                                      \
            (const __attribute__((address_space(1))) void*)(gB1 + (ck)),       \
            (__attribute__((address_space(3))) void*)&Bsh[bu][w * 1024 + 512], \
            16, 0, 0);                                                         \
    } while (0)

    G2_STAGE(0, 0);
    __syncthreads();

    for (int t = 0; t < 8; ++t) {
        const int cur = t & 1;
        if (t < 7) G2_STAGE(cur ^ 1, (t + 1) * 32);

        f16x8 af[4], bfr[4];
#pragma unroll
        for (int f = 0; f < 4; ++f) {
            af[f]  = *(const f16x8*)&Ash[cur][frag_off + (wr * 64 + f * 16) * 8];
            bfr[f] = *(const f16x8*)&Bsh[cur][frag_off + (wc * 64 + f * 16) * 8];
        }
#pragma unroll
        for (int i = 0; i < 4; ++i)
#pragma unroll
            for (int j = 0; j < 4; ++j)
                acc[i][j] = __builtin_amdgcn_mfma_f32_16x16x32_f16(
                    af[i], bfr[j], acc[i][j], 0, 0, 0);
        __syncthreads();
    }
#undef G2_STAGE

#pragma unroll
    for (int i = 0; i < 4; ++i) {
        const int jj = j0 + wr * 64 + i * 16 + rg * 4;
#pragma unroll
        for (int j = 0; j < 4; ++j) {
            const int nn = n0 + wc * 64 + j * 16 + cl;
#pragma unroll
            for (int r = 0; r < 4; ++r)
                Y[((size_t)b * CIN + jj + r) * NTOK + nn] =
                    acc[i][j][r] + bias[jj + r];
        }
    }
}

// ---------------------------------------------------------------------------
// Workspace (bytes):
//   Wc    768*512*2    =    786,432
//   bcomb pad          =      4,096
//   We16  512*256*2    =    262,144
//   QKb   8*4096*512*2 = 33,554,432
//   Vd    8*256*4096*2 = 16,777,216
//   xt    8*4096*512*2 = 33,554,432  (Obuf 16.8MB aliases xt after GEMM1)
//   total ~84.9 MB
// ---------------------------------------------------------------------------
extern "C" void kernel_launch(void* const* d_in, const int* in_sizes, int n_in,
                              void* d_out, int out_size, void* d_ws, size_t ws_size,
                              hipStream_t stream)
{
    const float* x    = (const float*)d_in[0];
    const float* Wr   = (const float*)d_in[1];
    const float* br   = (const float*)d_in[2];
    const float* Wqkv = (const float*)d_in[3];
    const float* We   = (const float*)d_in[4];
    const float* be   = (const float*)d_in[5];
    float* out = (float*)d_out;

    char* ws = (char*)d_ws;
    F16*   Wc    = (F16*)ws;      ws += 786432;
    float* bcomb = (float*)ws;    ws += 4096;
    F16*   We16  = (F16*)ws;      ws += 262144;
    F16*   QKb   = (F16*)ws;      ws += (size_t)BATCH * NTOK * 512 * 2;
    F16*   Vd    = (F16*)ws;      ws += (size_t)BATCH * CH * NTOK * 2;
    F16*   xt    = (F16*)ws;      // 33.5 MB
    F16*   Obuf  = (F16*)ws;      // aliases xt (16.8 MB), live after GEMM1

    fuse_weights_kernel<<<J3, 256, 0, stream>>>(Wr, br, Wqkv, Wc, bcomb);
    convert_we_kernel<<<CIN * CH / 256, 256, 0, stream>>>(We, We16);
    transpose_convert_kernel<<<dim3(NTOK / 64, CIN / 64, BATCH), 256, 0, stream>>>(x, xt);
    gemm1_kernel<<<dim3(NTOK / 128, J3 / 128, BATCH), 256, 0, stream>>>(
        Wc, xt, bcomb, QKb, Vd);
    attn_mfma_kernel<<<2048, 256, 0, stream>>>(QKb, Vd, Obuf);
    gemm2_kernel<<<dim3(NTOK / 128, CIN / 128, BATCH), 256, 0, stream>>>(
        We16, Obuf, be, out);
}